// Round 1
// baseline (304.451 us; speedup 1.0000x reference)
//
#include <hip/hip_runtime.h>
#include <cstdint>

// NT-Xent loss, fused:  S[r] = sum_{c!=r} exp((dot(n_r,n_c)-1)/tau)  via bf16-MFMA
// GEMM with fused exp+rowsum epilogue; loss from S + fp32 pair-dots.
//
// ws layout: [0, 8 MiB)      normalized embeddings, bf16, 8192 x 512
//            [8 MiB, +32 KB) S[8192] fp32 (atomic accum, memset 0)
//            then            acc2[2] fp32 {loss_sum, n_valid}

#define B_ROWS 4096
#define NROWS  8192
#define DIM    512

typedef unsigned short u16;

constexpr float TAU = 0.07f;
constexpr float INV_TAU = 1.0f / TAU;
constexpr float POS_THRESH = 0.2f;

constexpr int BM = 128, BN = 128, BK = 32;

using f32x4  = __attribute__((ext_vector_type(4))) float;
using bf16x8 = __attribute__((ext_vector_type(8))) short;

static __device__ __forceinline__ u16 f2bf(float f) {
  union { float f; uint32_t u; } v; v.f = f;
  uint32_t r = v.u + 0x7fffu + ((v.u >> 16) & 1u);  // RNE
  return (u16)(r >> 16);
}

static __device__ __forceinline__ void gload16(const u16* g, void* l) {
  __builtin_amdgcn_global_load_lds(
      (const __attribute__((address_space(1))) void*)g,
      (__attribute__((address_space(3))) void*)l, 16, 0, 0);
}

// ---------------- normalize: one wave per row, write bf16 ----------------
__global__ __launch_bounds__(256) void knorm(const float* __restrict__ ei,
                                             const float* __restrict__ ej,
                                             u16* __restrict__ E) {
  const int gw   = (blockIdx.x * 256 + threadIdx.x) >> 6;  // row 0..8191
  const int lane = threadIdx.x & 63;
  const float* src = (gw < B_ROWS) ? (ei + (size_t)gw * DIM)
                                   : (ej + (size_t)(gw - B_ROWS) * DIM);
  const float4* s4 = (const float4*)src;
  float4 a = s4[lane * 2 + 0];
  float4 b = s4[lane * 2 + 1];
  float ss = a.x*a.x + a.y*a.y + a.z*a.z + a.w*a.w
           + b.x*b.x + b.y*b.y + b.z*b.z + b.w*b.w;
#pragma unroll
  for (int m = 1; m < 64; m <<= 1) ss += __shfl_xor(ss, m);
  const float inv = 1.0f / sqrtf(ss);
  union { u16 us[8]; uint4 v; } pk;
  pk.us[0] = f2bf(a.x * inv); pk.us[1] = f2bf(a.y * inv);
  pk.us[2] = f2bf(a.z * inv); pk.us[3] = f2bf(a.w * inv);
  pk.us[4] = f2bf(b.x * inv); pk.us[5] = f2bf(b.y * inv);
  pk.us[6] = f2bf(b.z * inv); pk.us[7] = f2bf(b.w * inv);
  ((uint4*)(E + (size_t)gw * DIM))[lane] = pk.v;
}

// ------ fused Gram-GEMM + exp + row-sum (m97 structure, 128x128x32) ------
__global__ __launch_bounds__(256) void ksimlse(const u16* __restrict__ E,
                                               float* __restrict__ S) {
  __shared__ u16 As[BM * BK];  // 8 KiB, row-major [128][32]
  __shared__ u16 Bs[BN * BK];  // 8 KiB

  const int tid  = threadIdx.x;
  const int brow = (int)(blockIdx.x >> 6) * BM;   // 64 x 64 tile grid
  const int bcol = (int)(blockIdx.x & 63) * BN;
  const int wid  = tid >> 6;
  const int lane = tid & 63;
  const int wr   = (wid >> 1) * 64;   // wave row offset in tile
  const int wc   = (wid & 1) * 64;    // wave col offset in tile
  const int g    = lane >> 4;         // k-group / row-group
  const int lc   = lane & 15;

  // staging: thread t loads 8 bf16 (16B) from row (t>>2)+it*64, col (t&3)*8
  const int    srow  = tid >> 2;
  const int    scol  = (tid & 3) * 8;
  const size_t aBase = (size_t)(brow + srow) * DIM + scol;
  const size_t bBase = (size_t)(bcol + srow) * DIM + scol;

  f32x4 acc[4][4] = {};

  for (int kk = 0; kk < DIM; kk += BK) {
    __syncthreads();  // previous iter's ds_reads done before overwrite
#pragma unroll
    for (int it = 0; it < 2; ++it) {
      gload16(E + aBase + (size_t)it * 64 * DIM + kk, (char*)As + it * 4096 + tid * 16);
      gload16(E + bBase + (size_t)it * 64 * DIM + kk, (char*)Bs + it * 4096 + tid * 16);
    }
    __syncthreads();  // drains vmcnt(0): staged tile visible to all waves

    bf16x8 af[4], bfr[4];
#pragma unroll
    for (int mi = 0; mi < 4; ++mi)
      af[mi] = *(const bf16x8*)&As[(wr + mi * 16 + lc) * BK + g * 8];
#pragma unroll
    for (int ni = 0; ni < 4; ++ni)
      bfr[ni] = *(const bf16x8*)&Bs[(wc + ni * 16 + lc) * BK + g * 8];
#pragma unroll
    for (int mi = 0; mi < 4; ++mi)
#pragma unroll
      for (int ni = 0; ni < 4; ++ni)
        acc[mi][ni] = __builtin_amdgcn_mfma_f32_16x16x32_bf16(
            af[mi], bfr[ni], acc[mi][ni], 0, 0, 0);
  }

  // epilogue: exp((dot-1)/tau), mask diagonal exactly, row-sum 64 cols,
  // one atomicAdd per (row, wave).
  // C/D layout (16x16x32): col = lane&15, row = (lane>>4)*4 + j   [m89/m91]
#pragma unroll
  for (int mi = 0; mi < 4; ++mi) {
#pragma unroll
    for (int j = 0; j < 4; ++j) {
      const int Rg = brow + wr + mi * 16 + g * 4 + j;
      float rs = 0.0f;
#pragma unroll
      for (int ni = 0; ni < 4; ++ni) {
        const int Cg = bcol + wc + ni * 16 + lc;
        const float t = __expf((acc[mi][ni][j] - 1.0f) * INV_TAU);
        rs += (Rg == Cg) ? 0.0f : t;
      }
      rs += __shfl_xor(rs, 1);
      rs += __shfl_xor(rs, 2);
      rs += __shfl_xor(rs, 4);
      rs += __shfl_xor(rs, 8);
      if (lc == j) atomicAdd(&S[Rg], rs);  // 4 lanes (g=0..3), distinct rows
    }
  }
}

// --------- loss: one wave per pair k, fp32 dot + norms from raw inputs ---------
__global__ __launch_bounds__(256) void kloss(const float* __restrict__ ei,
                                             const float* __restrict__ ej,
                                             const float* __restrict__ dist,
                                             const float* __restrict__ S,
                                             float* __restrict__ acc2) {
  const int k    = (blockIdx.x * 256 + threadIdx.x) >> 6;
  const int lane = threadIdx.x & 63;
  const float4* pi = (const float4*)(ei + (size_t)k * DIM);
  const float4* pj = (const float4*)(ej + (size_t)k * DIM);
  float4 a0 = pi[lane * 2], a1 = pi[lane * 2 + 1];
  float4 b0 = pj[lane * 2], b1 = pj[lane * 2 + 1];
  float dot = a0.x*b0.x + a0.y*b0.y + a0.z*b0.z + a0.w*b0.w
            + a1.x*b1.x + a1.y*b1.y + a1.z*b1.z + a1.w*b1.w;
  float si  = a0.x*a0.x + a0.y*a0.y + a0.z*a0.z + a0.w*a0.w
            + a1.x*a1.x + a1.y*a1.y + a1.z*a1.z + a1.w*a1.w;
  float sj  = b0.x*b0.x + b0.y*b0.y + b0.z*b0.z + b0.w*b0.w
            + b1.x*b1.x + b1.y*b1.y + b1.z*b1.z + b1.w*b1.w;
#pragma unroll
  for (int m = 1; m < 64; m <<= 1) {
    dot += __shfl_xor(dot, m);
    si  += __shfl_xor(si, m);
    sj  += __shfl_xor(sj, m);
  }
  if (lane == 0) {
    float contrib = 0.0f, cnt = 0.0f;
    if (dist[k] < POS_THRESH) {
      const float s = dot / sqrtf(si * sj);  // cosine sim, fp32
      // lse[r] = log(S[r]) + 1/tau ; contrib = lse[k]+lse[k+B] - 2*s/tau
      contrib = logf(S[k]) + logf(S[k + B_ROWS]) + 2.0f * INV_TAU
              - 2.0f * s * INV_TAU;
      cnt = 2.0f;
    }
    atomicAdd(&acc2[0], contrib);
    atomicAdd(&acc2[1], cnt);
  }
}

__global__ void kfinal(const float* __restrict__ acc2, float* __restrict__ out) {
  const float ls = acc2[0], nv = acc2[1];
  out[0] = (nv > 0.0f) ? (ls / fmaxf(nv, 1.0f)) : 0.0f;
}

extern "C" void kernel_launch(void* const* d_in, const int* in_sizes, int n_in,
                              void* d_out, int out_size, void* d_ws, size_t ws_size,
                              hipStream_t stream) {
  const float* ei   = (const float*)d_in[0];
  const float* ej   = (const float*)d_in[1];
  const float* dist = (const float*)d_in[2];
  float* out = (float*)d_out;

  u16*   E    = (u16*)d_ws;
  float* S    = (float*)((char*)d_ws + (size_t)NROWS * DIM * sizeof(u16));
  float* acc2 = S + NROWS;

  hipMemsetAsync(S, 0, (NROWS + 2) * sizeof(float), stream);
  knorm<<<NROWS / 4, 256, 0, stream>>>(ei, ej, E);
  ksimlse<<<(NROWS / BM) * (NROWS / BN), 256, 0, stream>>>(E, S);
  kloss<<<B_ROWS / 4, 256, 0, stream>>>(ei, ej, dist, S, acc2);
  kfinal<<<1, 1, 0, stream>>>(acc2, out);
}

// Round 3
// 148.637 us; speedup vs baseline: 2.0483x; 2.0483x over previous
//
#include <hip/hip_runtime.h>
#include <cstdint>

// NT-Xent loss via symmetric bf16-MFMA Gram + fused exp/row-sum epilogue.
//  S[r] = sum_{c!=r} exp((dot(n_r,n_c)-1)/tau); lse[r] = log(S[r]) + 1/tau.
//  Symmetry: only tiles J>=I computed; off-diag tiles scatter row AND col sums.
// ws: [0, 8 MiB) E bf16 8192x512 | S[8192] f32 | pd[4096] f32 (pair cosines)

#define B_ROWS 4096
#define NROWS  8192
#define DIM    512

typedef unsigned short u16;

constexpr float INV_TAU    = 1.0f / 0.07f;
constexpr float POS_THRESH = 0.2f;
constexpr int BM = 128, BN = 128, BK = 32;

using f32x4  = __attribute__((ext_vector_type(4))) float;
using bf16x8 = __attribute__((ext_vector_type(8))) short;

static __device__ __forceinline__ u16 f2bf(float f) {
  union { float f; uint32_t u; } v; v.f = f;
  uint32_t r = v.u + 0x7fffu + ((v.u >> 16) & 1u);  // RNE
  return (u16)(r >> 16);
}

static __device__ __forceinline__ void gload16(const u16* g, void* l) {
  __builtin_amdgcn_global_load_lds(
      (const __attribute__((address_space(1))) void*)g,
      (__attribute__((address_space(3))) void*)l, 16, 0, 0);
}

// ---- knorm2: one wave per pair k. Normalize rows k and k+B to bf16,
//      compute fp32 pair cosine, zero S. ----
__global__ __launch_bounds__(256) void knorm2(const float* __restrict__ ei,
                                              const float* __restrict__ ej,
                                              u16* __restrict__ E,
                                              float* __restrict__ S,
                                              float* __restrict__ pd) {
  const int k    = (blockIdx.x * 256 + threadIdx.x) >> 6;  // pair 0..4095
  const int lane = threadIdx.x & 63;
  const float4* pi = (const float4*)(ei + (size_t)k * DIM);
  const float4* pj = (const float4*)(ej + (size_t)k * DIM);
  float4 a[2] = { pi[lane * 2], pi[lane * 2 + 1] };
  float4 b[2] = { pj[lane * 2], pj[lane * 2 + 1] };
  float si = 0.f, sj = 0.f, dot = 0.f;
#pragma unroll
  for (int h = 0; h < 2; ++h) {
    si  += a[h].x*a[h].x + a[h].y*a[h].y + a[h].z*a[h].z + a[h].w*a[h].w;
    sj  += b[h].x*b[h].x + b[h].y*b[h].y + b[h].z*b[h].z + b[h].w*b[h].w;
    dot += a[h].x*b[h].x + a[h].y*b[h].y + a[h].z*b[h].z + a[h].w*b[h].w;
  }
#pragma unroll
  for (int m = 1; m < 64; m <<= 1) {
    si += __shfl_xor(si, m); sj += __shfl_xor(sj, m); dot += __shfl_xor(dot, m);
  }
  const float invi = 1.0f / sqrtf(si);
  const float invj = 1.0f / sqrtf(sj);
  union { u16 us[8]; uint4 v; } pk;
#pragma unroll
  for (int h = 0; h < 2; ++h) {
    pk.us[h*4+0] = f2bf(a[h].x * invi); pk.us[h*4+1] = f2bf(a[h].y * invi);
    pk.us[h*4+2] = f2bf(a[h].z * invi); pk.us[h*4+3] = f2bf(a[h].w * invi);
  }
  ((uint4*)(E + (size_t)k * DIM))[lane] = pk.v;
#pragma unroll
  for (int h = 0; h < 2; ++h) {
    pk.us[h*4+0] = f2bf(b[h].x * invj); pk.us[h*4+1] = f2bf(b[h].y * invj);
    pk.us[h*4+2] = f2bf(b[h].z * invj); pk.us[h*4+3] = f2bf(b[h].w * invj);
  }
  ((uint4*)(E + (size_t)(k + B_ROWS) * DIM))[lane] = pk.v;
  if (lane == 0) {
    pd[k] = dot * invi * invj;
    S[k] = 0.0f; S[k + B_ROWS] = 0.0f;
  }
}

// ---- symmetric Gram-GEMM + exp + row/col sums (m97 structure) ----
__global__ __launch_bounds__(256) void ksimlse(const u16* __restrict__ E,
                                               float* __restrict__ S) {
  __shared__ u16 As[BM * BK];
  __shared__ u16 Bs[BN * BK];

  // triangular tile map: block t -> (I, J), J >= I, 64x64 tile grid
  const int t0 = blockIdx.x;
  int I = (int)(64.5f - sqrtf(4160.25f - 2.0f * (float)t0));
  if (I > 63) I = 63;
  int base = (129 * I - I * I) >> 1;
  if (base > t0) { --I; base = (129 * I - I * I) >> 1; }
  else {
    int nb = (129 * (I + 1) - (I + 1) * (I + 1)) >> 1;
    if (nb <= t0) { ++I; base = nb; }
  }
  const int J = I + (t0 - base);
  const int brow = I * BM, bcol = J * BN;
  const bool diag = (I == J);

  const int tid  = threadIdx.x;
  const int wid  = tid >> 6;
  const int lane = tid & 63;
  const int wr   = (wid >> 1) * 64;
  const int wc   = (wid & 1) * 64;
  const int g    = lane >> 4;
  const int lc   = lane & 15;

  const int    srow  = tid >> 2;
  const int    scol  = (tid & 3) * 8;
  const size_t aBase = (size_t)(brow + srow) * DIM + scol;
  const size_t bBase = (size_t)(bcol + srow) * DIM + scol;

  f32x4 acc[4][4] = {};

  for (int kk = 0; kk < DIM; kk += BK) {
    __syncthreads();
#pragma unroll
    for (int it = 0; it < 2; ++it) {
      gload16(E + aBase + (size_t)it * 64 * DIM + kk, (char*)As + it * 4096 + tid * 16);
      gload16(E + bBase + (size_t)it * 64 * DIM + kk, (char*)Bs + it * 4096 + tid * 16);
    }
    __syncthreads();

    bf16x8 af[4], bfr[4];
#pragma unroll
    for (int mi = 0; mi < 4; ++mi)
      af[mi] = *(const bf16x8*)&As[(wr + mi * 16 + lc) * BK + g * 8];
#pragma unroll
    for (int ni = 0; ni < 4; ++ni)
      bfr[ni] = *(const bf16x8*)&Bs[(wc + ni * 16 + lc) * BK + g * 8];
#pragma unroll
    for (int mi = 0; mi < 4; ++mi)
#pragma unroll
      for (int ni = 0; ni < 4; ++ni)
        acc[mi][ni] = __builtin_amdgcn_mfma_f32_16x16x32_bf16(
            af[mi], bfr[ni], acc[mi][ni], 0, 0, 0);
  }

  // epilogue: C/D layout col=lane&15, row=(lane>>4)*4+j  [m89/m91]
  float cs[4] = {0.f, 0.f, 0.f, 0.f};
#pragma unroll
  for (int mi = 0; mi < 4; ++mi) {
#pragma unroll
    for (int j = 0; j < 4; ++j) {
      const int Rg = brow + wr + mi * 16 + g * 4 + j;
      float rs = 0.0f;
#pragma unroll
      for (int ni = 0; ni < 4; ++ni) {
        const int Cg = bcol + wc + ni * 16 + lc;
        float e = __expf((acc[mi][ni][j] - 1.0f) * INV_TAU);
        if (diag && Rg == Cg) e = 0.0f;
        rs += e;
        cs[ni] += e;
      }
      rs += __shfl_xor(rs, 1);
      rs += __shfl_xor(rs, 2);
      rs += __shfl_xor(rs, 4);
      rs += __shfl_xor(rs, 8);
      if (lc == j) atomicAdd(&S[Rg], rs);
    }
  }
  if (!diag) {  // column sums -> S[c] (the mirrored half)
#pragma unroll
    for (int ni = 0; ni < 4; ++ni) {
      float c = cs[ni];
      c += __shfl_xor(c, 16);
      c += __shfl_xor(c, 32);
      if (g == 0) atomicAdd(&S[bcol + wc + ni * 16 + lc], c);
    }
  }
}

// ---- final: single block folds per-pair loss, no global atomics ----
__global__ __launch_bounds__(256) void kfinal256(const float* __restrict__ dist,
                                                 const float* __restrict__ pd,
                                                 const float* __restrict__ S,
                                                 float* __restrict__ out) {
  const int tid = threadIdx.x;
  float ls = 0.0f, nv = 0.0f;
  for (int it = 0; it < B_ROWS / 256; ++it) {
    const int k = it * 256 + tid;
    if (dist[k] < POS_THRESH) {
      ls += logf(S[k]) + logf(S[k + B_ROWS]) + 2.0f * INV_TAU
          - 2.0f * pd[k] * INV_TAU;
      nv += 2.0f;
    }
  }
#pragma unroll
  for (int m = 1; m < 64; m <<= 1) {
    ls += __shfl_xor(ls, m); nv += __shfl_xor(nv, m);
  }
  __shared__ float sl[4], sn[4];
  if ((tid & 63) == 0) { sl[tid >> 6] = ls; sn[tid >> 6] = nv; }
  __syncthreads();
  if (tid == 0) {
    const float L = sl[0] + sl[1] + sl[2] + sl[3];
    const float N = sn[0] + sn[1] + sn[2] + sn[3];
    out[0] = (N > 0.0f) ? (L / fmaxf(N, 1.0f)) : 0.0f;
  }
}

extern "C" void kernel_launch(void* const* d_in, const int* in_sizes, int n_in,
                              void* d_out, int out_size, void* d_ws, size_t ws_size,
                              hipStream_t stream) {
  const float* ei   = (const float*)d_in[0];
  const float* ej   = (const float*)d_in[1];
  const float* dist = (const float*)d_in[2];
  float* out = (float*)d_out;

  u16*   E  = (u16*)d_ws;
  float* S  = (float*)((char*)d_ws + (size_t)NROWS * DIM * sizeof(u16));
  float* pd = S + NROWS;

  knorm2<<<B_ROWS / 4, 256, 0, stream>>>(ei, ej, E, S, pd);
  ksimlse<<<2080, 256, 0, stream>>>(E, S);  // 64 diag + 2016 upper tiles
  kfinal256<<<1, 256, 0, stream>>>(dist, pd, S, out);
}

// Round 6
// 143.088 us; speedup vs baseline: 2.1277x; 1.0388x over previous
//
#include <hip/hip_runtime.h>
#include <cstdint>

// NT-Xent loss via symmetric bf16-MFMA Gram + fused exp/row-sum epilogue.
//  S[r] = sum_{c!=r} exp((dot(n_r,n_c)-1)/tau); lse[r] = log(S[r]) + 1/tau.
//  Symmetry: only tiles J>=I computed; off-diag tiles scatter row AND col sums.
//  R5/R6: 2-phase double-buffered LDS pipeline in the K-loop (T3 minimum form):
//      issue next-tile global_load_lds BEFORE ds_read+MFMA of current tile,
//      one barrier per K-step (structural vmcnt(0)+lgkmcnt(0) drain).
// ws: [0, 8 MiB) E bf16 8192x512 | S[8192] f32 | pd[4096] f32 (pair cosines)

#define B_ROWS 4096
#define NROWS  8192
#define DIM    512

typedef unsigned short u16;

constexpr float INV_TAU    = 1.0f / 0.07f;
constexpr float POS_THRESH = 0.2f;
constexpr int BM = 128, BN = 128, BK = 32;
constexpr int KSTEPS = DIM / BK;   // 16

using f32x4  = __attribute__((ext_vector_type(4))) float;
using bf16x8 = __attribute__((ext_vector_type(8))) short;

static __device__ __forceinline__ u16 f2bf(float f) {
  union { float f; uint32_t u; } v; v.f = f;
  uint32_t r = v.u + 0x7fffu + ((v.u >> 16) & 1u);  // RNE
  return (u16)(r >> 16);
}

static __device__ __forceinline__ void gload16(const u16* g, void* l) {
  __builtin_amdgcn_global_load_lds(
      (const __attribute__((address_space(1))) void*)g,
      (__attribute__((address_space(3))) void*)l, 16, 0, 0);
}

// ---- knorm2: one wave per pair k. Normalize rows k and k+B to bf16,
//      compute fp32 pair cosine, zero S. (unchanged from R3) ----
__global__ __launch_bounds__(256) void knorm2(const float* __restrict__ ei,
                                              const float* __restrict__ ej,
                                              u16* __restrict__ E,
                                              float* __restrict__ S,
                                              float* __restrict__ pd) {
  const int k    = (blockIdx.x * 256 + threadIdx.x) >> 6;  // pair 0..4095
  const int lane = threadIdx.x & 63;
  const float4* pi = (const float4*)(ei + (size_t)k * DIM);
  const float4* pj = (const float4*)(ej + (size_t)k * DIM);
  float4 a[2] = { pi[lane * 2], pi[lane * 2 + 1] };
  float4 b[2] = { pj[lane * 2], pj[lane * 2 + 1] };
  float si = 0.f, sj = 0.f, dot = 0.f;
#pragma unroll
  for (int h = 0; h < 2; ++h) {
    si  += a[h].x*a[h].x + a[h].y*a[h].y + a[h].z*a[h].z + a[h].w*a[h].w;
    sj  += b[h].x*b[h].x + b[h].y*b[h].y + b[h].z*b[h].z + b[h].w*b[h].w;
    dot += a[h].x*b[h].x + a[h].y*b[h].y + a[h].z*b[h].z + a[h].w*b[h].w;
  }
#pragma unroll
  for (int m = 1; m < 64; m <<= 1) {
    si += __shfl_xor(si, m); sj += __shfl_xor(sj, m); dot += __shfl_xor(dot, m);
  }
  const float invi = 1.0f / sqrtf(si);
  const float invj = 1.0f / sqrtf(sj);
  union { u16 us[8]; uint4 v; } pk;
#pragma unroll
  for (int h = 0; h < 2; ++h) {
    pk.us[h*4+0] = f2bf(a[h].x * invi); pk.us[h*4+1] = f2bf(a[h].y * invi);
    pk.us[h*4+2] = f2bf(a[h].z * invi); pk.us[h*4+3] = f2bf(a[h].w * invi);
  }
  ((uint4*)(E + (size_t)k * DIM))[lane] = pk.v;
#pragma unroll
  for (int h = 0; h < 2; ++h) {
    pk.us[h*4+0] = f2bf(b[h].x * invj); pk.us[h*4+1] = f2bf(b[h].y * invj);
    pk.us[h*4+2] = f2bf(b[h].z * invj); pk.us[h*4+3] = f2bf(b[h].w * invj);
  }
  ((uint4*)(E + (size_t)(k + B_ROWS) * DIM))[lane] = pk.v;
  if (lane == 0) {
    pd[k] = dot * invi * invj;
    S[k] = 0.0f; S[k + B_ROWS] = 0.0f;
  }
}

// ---- symmetric Gram-GEMM + exp + row/col sums, 2-phase dbuf pipeline ----
__global__ __launch_bounds__(256) void ksimlse(const u16* __restrict__ E,
                                               float* __restrict__ S) {
  __shared__ u16 As[2][BM * BK];  // 2 x 8 KiB
  __shared__ u16 Bs[2][BN * BK];  // 2 x 8 KiB

  // triangular tile map: block t -> (I, J), J >= I, 64x64 tile grid
  const int t0 = blockIdx.x;
  int I = (int)(64.5f - sqrtf(4160.25f - 2.0f * (float)t0));
  if (I > 63) I = 63;
  int base = (129 * I - I * I) >> 1;
  if (base > t0) { --I; base = (129 * I - I * I) >> 1; }
  else {
    int nb = (129 * (I + 1) - (I + 1) * (I + 1)) >> 1;
    if (nb <= t0) { ++I; base = nb; }
  }
  const int J = I + (t0 - base);
  const int brow = I * BM, bcol = J * BN;
  const bool diag = (I == J);

  const int tid  = threadIdx.x;
  const int wid  = tid >> 6;
  const int lane = tid & 63;
  const int wr   = (wid >> 1) * 64;
  const int wc   = (wid & 1) * 64;
  const int g    = lane >> 4;
  const int lc   = lane & 15;

  const int    srow  = tid >> 2;
  const int    scol  = (tid & 3) * 8;
  const size_t aBase = (size_t)(brow + srow) * DIM + scol;
  const size_t bBase = (size_t)(bcol + srow) * DIM + scol;

  // stage K-step kk into buffer b (linear LDS dest, per-lane global src)
  auto stage = [&](int b, int kk) {
#pragma unroll
    for (int it = 0; it < 2; ++it) {
      gload16(E + aBase + (size_t)it * 64 * DIM + kk,
              (char*)As + b * 8192 + it * 4096 + tid * 16);
      gload16(E + bBase + (size_t)it * 64 * DIM + kk,
              (char*)Bs + b * 8192 + it * 4096 + tid * 16);
    }
  };

  f32x4 acc[4][4] = {};

  stage(0, 0);
  __syncthreads();                       // buf0 staged (vmcnt(0) drain)

#pragma unroll 1
  for (int t = 0; t < KSTEPS; ++t) {
    const int cur = t & 1;
    if (t + 1 < KSTEPS) stage(cur ^ 1, (t + 1) * BK);  // prefetch FIRST

    bf16x8 af[4], bfr[4];
#pragma unroll
    for (int mi = 0; mi < 4; ++mi)
      af[mi] = *(const bf16x8*)&As[cur][(wr + mi * 16 + lc) * BK + g * 8];
#pragma unroll
    for (int ni = 0; ni < 4; ++ni)
      bfr[ni] = *(const bf16x8*)&Bs[cur][(wc + ni * 16 + lc) * BK + g * 8];
#pragma unroll
    for (int mi = 0; mi < 4; ++mi)
#pragma unroll
      for (int ni = 0; ni < 4; ++ni)
        acc[mi][ni] = __builtin_amdgcn_mfma_f32_16x16x32_bf16(
            af[mi], bfr[ni], acc[mi][ni], 0, 0, 0);

    __syncthreads();  // one barrier/K-step: drains prefetch (vmcnt) + ds_reads
  }

  // epilogue: C/D layout col=lane&15, row=(lane>>4)*4+j  [m89/m91]
  float cs[4] = {0.f, 0.f, 0.f, 0.f};
#pragma unroll
  for (int mi = 0; mi < 4; ++mi) {
#pragma unroll
    for (int j = 0; j < 4; ++j) {
      const int Rg = brow + wr + mi * 16 + g * 4 + j;
      float rs = 0.0f;
#pragma unroll
      for (int ni = 0; ni < 4; ++ni) {
        const int Cg = bcol + wc + ni * 16 + lc;
        float e = __expf((acc[mi][ni][j] - 1.0f) * INV_TAU);
        if (diag && Rg == Cg) e = 0.0f;
        rs += e;
        cs[ni] += e;
      }
      rs += __shfl_xor(rs, 1);
      rs += __shfl_xor(rs, 2);
      rs += __shfl_xor(rs, 4);
      rs += __shfl_xor(rs, 8);
      if (lc == j) atomicAdd(&S[Rg], rs);
    }
  }
  if (!diag) {  // column sums -> S[c] (the mirrored half)
#pragma unroll
    for (int ni = 0; ni < 4; ++ni) {
      float c = cs[ni];
      c += __shfl_xor(c, 16);
      c += __shfl_xor(c, 32);
      if (g == 0) atomicAdd(&S[bcol + wc + ni * 16 + lc], c);
    }
  }
}

// ---- final: single block folds per-pair loss, no global atomics ----
__global__ __launch_bounds__(256) void kfinal256(const float* __restrict__ dist,
                                                 const float* __restrict__ pd,
                                                 const float* __restrict__ S,
                                                 float* __restrict__ out) {
  const int tid = threadIdx.x;
  float ls = 0.0f, nv = 0.0f;
  for (int it = 0; it < B_ROWS / 256; ++it) {
    const int k = it * 256 + tid;
    if (dist[k] < POS_THRESH) {
      ls += logf(S[k]) + logf(S[k + B_ROWS]) + 2.0f * INV_TAU
          - 2.0f * pd[k] * INV_TAU;
      nv += 2.0f;
    }
  }
#pragma unroll
  for (int m = 1; m < 64; m <<= 1) {
    ls += __shfl_xor(ls, m); nv += __shfl_xor(nv, m);
  }
  __shared__ float sl[4], sn[4];
  if ((tid & 63) == 0) { sl[tid >> 6] = ls; sn[tid >> 6] = nv; }
  __syncthreads();
  if (tid == 0) {
    const float L = sl[0] + sl[1] + sl[2] + sl[3];
    const float N = sn[0] + sn[1] + sn[2] + sn[3];
    out[0] = (N > 0.0f) ? (L / fmaxf(N, 1.0f)) : 0.0f;
  }
}

extern "C" void kernel_launch(void* const* d_in, const int* in_sizes, int n_in,
                              void* d_out, int out_size, void* d_ws, size_t ws_size,
                              hipStream_t stream) {
  const float* ei   = (const float*)d_in[0];
  const float* ej   = (const float*)d_in[1];
  const float* dist = (const float*)d_in[2];
  float* out = (float*)d_out;

  u16*   E  = (u16*)d_ws;
  float* S  = (float*)((char*)d_ws + (size_t)NROWS * DIM * sizeof(u16));
  float* pd = S + NROWS;

  knorm2<<<B_ROWS / 4, 256, 0, stream>>>(ei, ej, E, S, pd);
  ksimlse<<<2080, 256, 0, stream>>>(E, S);  // 64 diag + 2016 upper tiles
  kfinal256<<<1, 256, 0, stream>>>(dist, pd, S, out);
}